// Round 2
// baseline (257.393 us; speedup 1.0000x reference)
//
#include <hip/hip_runtime.h>
#include <hip/hip_bf16.h>

#define NB 32
#define NS 1024
#define ND 768
#define BS_TOT (NB * NS)  // 32768

// sim scale = 1 / (0.7 * sqrt(768))
#define SCALE 0.05154913f

typedef __attribute__((ext_vector_type(8))) short bf16x8;  // 8 bf16 = 4 VGPRs
typedef __attribute__((ext_vector_type(4))) float f32x4;

__device__ __forceinline__ unsigned short f2bf(float f) {
  __hip_bfloat16 h = __float2bfloat16(f);
  return *reinterpret_cast<unsigned short*>(&h);
}

__device__ __forceinline__ void gload_lds16(const unsigned short* g, short* l) {
  __builtin_amdgcn_global_load_lds(
      (const __attribute__((address_space(1))) unsigned int*)g,
      (__attribute__((address_space(3))) unsigned int*)l,
      16 /*bytes*/, 0 /*offset*/, 0 /*aux*/);
}

// ---------------- Kernel 1: fp32 -> bf16 convert ----------------
__global__ void cvt_kernel(const float* __restrict__ in,
                           unsigned short* __restrict__ out) {
  int i = (blockIdx.x * 256 + threadIdx.x) * 4;
  float4 v = *reinterpret_cast<const float4*>(in + i);
  ushort4 o;
  o.x = f2bf(v.x);
  o.y = f2bf(v.y);
  o.z = f2bf(v.z);
  o.w = f2bf(v.w);
  *reinterpret_cast<ushort4*>(out + i) = o;
}

// ---------------- Kernel 2: per-anchor metadata ----------------
// Handles labels arriving as either int32 or raw int64 (little-endian): if
// int64, every odd 32-bit word of the label buffer is the zero high-word.
// All blocks sniff the same window [0,2048 words) -> consistent decision.
__global__ void meta_kernel(const int* __restrict__ lr,
                            float* __restrict__ invN,
                            float* __restrict__ invGS,
                            float* __restrict__ numneg,
                            int* __restrict__ labI,
                            float* __restrict__ out) {
  __shared__ int cnt[16];
  __shared__ int is64;
  int b = blockIdx.x, t = threadIdx.x;
  if (t == 0) is64 = 1;
  if (t < 16) cnt[t] = 0;
  __syncthreads();
  int bad = 0;
  for (int k = t; k < 1024; k += 256) bad |= lr[2 * k + 1];
  if (bad) atomicAnd(&is64, 0);
  __syncthreads();
  const bool i64 = (is64 != 0);
  for (int i = t; i < NS; i += 256) {
    int gi = b * NS + i;
    int lab = (i64 ? lr[2 * gi] : lr[gi]) & 15;
    atomicAdd(&cnt[lab], 1);
  }
  __syncthreads();
  for (int i = t; i < NS; i += 256) {
    int gi = b * NS + i;
    int lab = (i64 ? lr[2 * gi] : lr[gi]) & 15;
    int gs = cnt[lab];
    int nn = NS - gs;
    invN[gi] = nn > 0 ? 1.0f / (float)nn : 0.0f;
    invGS[gi] = 1.0f / (float)gs;
    numneg[gi] = (float)nn;
    labI[gi] = lab;
  }
  if (b == 0 && t == 0) out[0] = 0.0f;  // d_out is poisoned before each launch
}

// ---------------- Kernel 3: fused Gram + SupCon epilogue ----------------
// Grid: 512 blocks = 32 batches x 8 row-tiles(128) x 2 column-splits(512 cols).
// Block: 256 threads = 4 waves; wave (wr,wc) computes 64x64 of the 128x128 tile
// per column-tile via 4x4 grid of 16x16x32 bf16 MFMAs, K-loop over D=768.
// Per-row accumulators are reduced over l15 lanes (shuffle), then over the two
// wc waves (LDS) -- the wc combine was the round-1 bug (last-writer-wins race).
__global__ __launch_bounds__(256, 2) void gram_kernel(
    const unsigned short* __restrict__ featB, const int* __restrict__ labI,
    const float* __restrict__ invN, float* __restrict__ negP,
    float* __restrict__ posP, float* __restrict__ nltP) {
  const int bid = blockIdx.x;
  const int cs = bid & 1;
  const int rt = (bid >> 1) & 7;
  const int b = bid >> 4;

  const int tid = threadIdx.x;
  const int lane = tid & 63;
  const int w = tid >> 6;
  const int wr = w >> 1, wc = w & 1;
  const int quad = lane >> 4, l15 = lane & 15;

  __shared__ alignas(16) short As[128 * 32];  // 8 KB, row-major [row][k]
  __shared__ alignas(16) short Bs[128 * 32];  // 8 KB, row-major [col][k]
  __shared__ float redL[2][3][128];           // [wc][neg/pos/nlt][row], 3 KB

  const int rowBase = rt * 128;  // within-batch row of this block's tile

  // Per-row metadata (C/D layout rows: quad*4 + r within each 16-row subtile)
  int labr[4][4];
  float eN[4][4];  // SCALE * invN_i  (exp argument multiplier on raw acc)
  const int ibase = b * NS + rowBase + wr * 64;
#pragma unroll
  for (int rs = 0; rs < 4; ++rs)
#pragma unroll
    for (int r = 0; r < 4; ++r) {
      int idx = ibase + rs * 16 + quad * 4 + r;
      labr[rs][r] = labI[idx];
      eN[rs][r] = invN[idx] * SCALE;
    }

  float neg[4][4], pos[4][4], nlt[4][4];
#pragma unroll
  for (int rs = 0; rs < 4; ++rs)
#pragma unroll
    for (int r = 0; r < 4; ++r) {
      neg[rs][r] = 0.0f;
      pos[rs][r] = 0.0f;
      nlt[rs][r] = 0.0f;
    }

  const size_t featA = (size_t)(b * NS + rowBase) * ND;

  for (int ct = 0; ct < 4; ++ct) {
    const int colBase = cs * 512 + ct * 128;
    const size_t featBb = (size_t)(b * NS + colBase) * ND;

    f32x4 acc[4][4];
    const f32x4 zv = {0.0f, 0.0f, 0.0f, 0.0f};
#pragma unroll
    for (int rs = 0; rs < 4; ++rs)
#pragma unroll
      for (int csb = 0; csb < 4; ++csb) acc[rs][csb] = zv;

    for (int k0 = 0; k0 < ND; k0 += 32) {
      __syncthreads();  // previous iteration's ds_reads done before restage
      // Stage A-tile 128x32 and B-tile 128x32 (16 B/lane, wave-contiguous LDS)
#pragma unroll
      for (int rnd = 0; rnd < 2; ++rnd) {
        int s = rnd * 256 + tid;
        int row = s >> 2, ch = s & 3;
        gload_lds16(featB + featA + (size_t)row * ND + k0 + ch * 8, &As[s * 8]);
      }
#pragma unroll
      for (int rnd = 0; rnd < 2; ++rnd) {
        int s = rnd * 256 + tid;
        int row = s >> 2, ch = s & 3;
        gload_lds16(featB + featBb + (size_t)row * ND + k0 + ch * 8, &Bs[s * 8]);
      }
      __syncthreads();  // vmcnt drain: staging visible

      bf16x8 av[4], bv[4];
#pragma unroll
      for (int rs = 0; rs < 4; ++rs)
        av[rs] = *reinterpret_cast<const bf16x8*>(
            &As[(wr * 64 + rs * 16 + l15) * 32 + quad * 8]);
#pragma unroll
      for (int csb = 0; csb < 4; ++csb)
        bv[csb] = *reinterpret_cast<const bf16x8*>(
            &Bs[(wc * 64 + csb * 16 + l15) * 32 + quad * 8]);
#pragma unroll
      for (int rs = 0; rs < 4; ++rs)
#pragma unroll
        for (int csb = 0; csb < 4; ++csb)
          acc[rs][csb] = __builtin_amdgcn_mfma_f32_16x16x32_bf16(
              av[rs], bv[csb], acc[rs][csb], 0, 0, 0);
    }

    // Fused epilogue for this 128x128 sim tile
#pragma unroll
    for (int csb = 0; csb < 4; ++csb) {
      int jl = colBase + wc * 64 + csb * 16 + l15;  // within-batch column j
      int labc = labI[b * NS + jl];
#pragma unroll
      for (int rs = 0; rs < 4; ++rs)
#pragma unroll
        for (int r = 0; r < 4; ++r) {
          int ig = rowBase + wr * 64 + rs * 16 + quad * 4 + r;
          float a = acc[rs][csb][r];
          bool same = (labc == labr[rs][r]);
          float e = __expf(a * eN[rs][r]);
          if (!same) {
            neg[rs][r] += e;
          } else if (jl > ig) {
            pos[rs][r] += a * SCALE;
            nlt[rs][r] += 1.0f;
          }
        }
    }
  }

  // Reduce across the 16 lanes (l15) sharing each output row...
#pragma unroll
  for (int rs = 0; rs < 4; ++rs)
#pragma unroll
    for (int r = 0; r < 4; ++r) {
      float n_ = neg[rs][r], p_ = pos[rs][r], c_ = nlt[rs][r];
#pragma unroll
      for (int m = 1; m < 16; m <<= 1) {
        n_ += __shfl_xor(n_, m);
        p_ += __shfl_xor(p_, m);
        c_ += __shfl_xor(c_, m);
      }
      if (l15 == 0) {
        int row = wr * 64 + rs * 16 + quad * 4 + r;  // block-relative row
        redL[wc][0][row] = n_;
        redL[wc][1][row] = p_;
        redL[wc][2][row] = c_;
      }
    }
  // ...then combine the two wc column-halves (round-1 bugfix) and store.
  __syncthreads();
  if (tid < 128) {
    int o = cs * BS_TOT + b * NS + rowBase + tid;
    negP[o] = redL[0][0][tid] + redL[1][0][tid];
    posP[o] = redL[0][1][tid] + redL[1][1][tid];
    nltP[o] = redL[0][2][tid] + redL[1][2][tid];
  }
}

// ---------------- Kernel 4: combine partials -> loss ----------------
__global__ void final_kernel(const float* __restrict__ negP,
                             const float* __restrict__ posP,
                             const float* __restrict__ nltP,
                             const float* __restrict__ invGS,
                             const float* __restrict__ numneg,
                             float* __restrict__ out) {
  int idx = blockIdx.x * 256 + threadIdx.x;
  float neg = negP[idx] + negP[BS_TOT + idx];
  float pos = posP[idx] + posP[BS_TOT + idx];
  float nl = nltP[idx] + nltP[BS_TOT + idx];
  float pa = 0.0f;
  if (numneg[idx] > 0.0f) pa = -(pos - nl * __logf(neg)) * invGS[idx];
#pragma unroll
  for (int m = 1; m < 64; m <<= 1) pa += __shfl_xor(pa, m);
  __shared__ float wsum[4];
  if ((threadIdx.x & 63) == 0) wsum[threadIdx.x >> 6] = pa;
  __syncthreads();
  if (threadIdx.x == 0) {
    float s = wsum[0] + wsum[1] + wsum[2] + wsum[3];
    atomicAdd(out, s * (1.0f / (float)NS));
  }
}

extern "C" void kernel_launch(void* const* d_in, const int* in_sizes, int n_in,
                              void* d_out, int out_size, void* d_ws,
                              size_t ws_size, hipStream_t stream) {
  (void)in_sizes;
  (void)n_in;
  (void)out_size;
  (void)ws_size;
  const float* feat = (const float*)d_in[0];
  const int* labels = (const int*)d_in[1];
  float* out = (float*)d_out;

  char* w = (char*)d_ws;
  unsigned short* featB = (unsigned short*)w;  // bf16 features, 50,331,648 B
  size_t off = (size_t)NB * NS * ND * 2;
  float* invN = (float*)(w + off);
  off += (size_t)BS_TOT * 4;
  float* invGS = (float*)(w + off);
  off += (size_t)BS_TOT * 4;
  float* numneg = (float*)(w + off);
  off += (size_t)BS_TOT * 4;
  int* labI = (int*)(w + off);
  off += (size_t)BS_TOT * 4;
  float* negP = (float*)(w + off);
  off += (size_t)2 * BS_TOT * 4;
  float* posP = (float*)(w + off);
  off += (size_t)2 * BS_TOT * 4;
  float* nltP = (float*)(w + off);
  off += (size_t)2 * BS_TOT * 4;
  // total ws usage ~51.6 MB

  cvt_kernel<<<(NB * NS * ND) / 1024, 256, 0, stream>>>(feat, featB);
  meta_kernel<<<NB, 256, 0, stream>>>(labels, invN, invGS, numneg, labI, out);
  gram_kernel<<<512, 256, 0, stream>>>(featB, labI, invN, negP, posP, nltP);
  final_kernel<<<BS_TOT / 256, 256, 0, stream>>>(negP, posP, nltP, invGS,
                                                 numneg, out);
}